// Round 10
// baseline (1975.363 us; speedup 1.0000x reference)
//
#include <hip/hip_runtime.h>
#include <hip/hip_bf16.h>

#define Hh   64      // LSTM hidden
#define G4   256     // 4*H gate width
#define Dd   128     // input feature dim
#define Bsz  256     // batch
#define Tt   1024    // time steps
#define NOUT 10      // dense classes

typedef __bf16  bf16x8 __attribute__((ext_vector_type(8)));
typedef float   f32x4v __attribute__((ext_vector_type(4)));

// Gate-column permutation: z-row rho <-> (gate g, h-index hidx) chosen so the
// 16x16x32 D-fragment (row=(l>>4)*4+r, col=l&15) lands all 4 gates of
// hidx = 32s + 8kq + 4d2 + dl in lane l = kq*16+m == the lane that must hold
// h[hidx] for the next step's B-fragment (k=(l>>4)*8+j).
//   rho = 64g + 32s + 16d2 + 4kq + dl ;  hidx = 32s + 8kq + 4d2 + dl
__device__ __forceinline__ int rho_origcol(int rho) {
    const int g  = rho >> 6;
    const int s  = (rho >> 5) & 1;
    const int d2 = (rho >> 4) & 1;
    const int kq = (rho >> 2) & 3;
    const int dl = rho & 3;
    return g * 64 + (32 * s + 8 * kq + 4 * d2 + dl);
}

// xws layout (k2-native, bf16):
//   byte(b, t, rho) = (b>>4)*8MB + t*8192 + (rho>>5)*1024
//                     + ((rho>>2)&3)*256 + (b&15)*16 + ((rho>>4)&1)*8 + (rho&3)*2
// lane l = kq*16+m of group g16 owns the contiguous 16B at
//   t*8192 + ttp*1024 + l*16  for ttp = 0..7  (8 x 1KB coalesced per step).

// async 16B/lane global->LDS DMA (wave-uniform LDS base + lane*16 dest)
__device__ __forceinline__ void gld_lds16(const void* g, void* l) {
    __builtin_amdgcn_global_load_lds(
        (const __attribute__((address_space(1))) unsigned int*)g,
        (__attribute__((address_space(3))) unsigned int*)l, 16, 0, 0);
}

// ---------------------------------------------------------------------------
// K0: Wt[rho][k] = bf16(scale * W[k][origcol]), bias2[rho] = scale*b + offs.
// scale = 0.2 for i,f,o gates (hard-sigmoid pre-scale), 1 for g gate.
// ---------------------------------------------------------------------------
__global__ __launch_bounds__(128)
void k0_prep(const float* __restrict__ W, const float* __restrict__ b,
             __bf16* __restrict__ Wt, float* __restrict__ bias2) {
    const int rho = blockIdx.x;   // 0..255
    const int k   = threadIdx.x;  // 0..127
    const int col = rho_origcol(rho);
    const bool isg = ((rho >> 6) == 2);
    const float sc = isg ? 1.f : 0.2f;
    Wt[(size_t)rho * Dd + k] = (__bf16)(sc * W[(size_t)k * G4 + col]);
    if (k == 0) bias2[rho] = sc * b[col] + (isg ? 0.f : 0.5f);
}

// ---------------------------------------------------------------------------
// K1: xw = x @ Wt + bias2 via mfma_f32_16x16x32_bf16, stored into the
// k2-native xws layout (verbatim from the passing R8 kernel).
// ---------------------------------------------------------------------------
#define K1_RT 8   // 16-row tiles per block -> 128 rows/block (one batch b per block)

__global__ __launch_bounds__(256)
void k1_mfma(const float* __restrict__ x, const __bf16* __restrict__ Wt,
             const float* __restrict__ bias, __bf16* __restrict__ xws) {
    const int tid = threadIdx.x;
    const int w   = tid >> 6;      // wave 0..3
    const int l   = tid & 63;
    const int r16 = l & 15;
    const int kq  = l >> 4;        // 0..3 (A-row quad)
    const size_t rowbase = (size_t)blockIdx.x * (16 * K1_RT);

    const int bb   = (int)(rowbase >> 10);      // batch (uniform per block)
    const size_t gm_base = ((size_t)(bb >> 4) << 23) + (size_t)(bb & 15) * 16;
    const int lane_off = (r16 >> 2) * 256 + (r16 & 3) * 2;

    bf16x8 bfr[4][4];
    float  bval[4];
#pragma unroll
    for (int ct = 0; ct < 4; ++ct) {
        const int col = w * 64 + ct * 16 + r16;
        const __bf16* wp = Wt + (size_t)col * Dd + kq * 8;
#pragma unroll
        for (int kk = 0; kk < 4; ++kk)
            bfr[ct][kk] = *(const bf16x8*)(wp + kk * 32);
        bval[ct] = bias[col];
    }

    for (int rt = 0; rt < K1_RT; ++rt) {
        const size_t arow = rowbase + rt * 16 + r16;
        const float* xr = x + arow * Dd + kq * 8;
        bf16x8 afr[4];
#pragma unroll
        for (int kk = 0; kk < 4; ++kk) {
            const float4 lo = *(const float4*)(xr + kk * 32);
            const float4 hi = *(const float4*)(xr + kk * 32 + 4);
            afr[kk][0] = (__bf16)lo.x; afr[kk][1] = (__bf16)lo.y;
            afr[kk][2] = (__bf16)lo.z; afr[kk][3] = (__bf16)lo.w;
            afr[kk][4] = (__bf16)hi.x; afr[kk][5] = (__bf16)hi.y;
            afr[kk][6] = (__bf16)hi.z; afr[kk][7] = (__bf16)hi.w;
        }
        f32x4v acc[4];
#pragma unroll
        for (int ct = 0; ct < 4; ++ct)
            acc[ct] = (f32x4v){bval[ct], bval[ct], bval[ct], bval[ct]};
#pragma unroll
        for (int ct = 0; ct < 4; ++ct)
#pragma unroll
            for (int kk = 0; kk < 4; ++kk)
                acc[ct] = __builtin_amdgcn_mfma_f32_16x16x32_bf16(
                              afr[kk], bfr[ct][kk], acc[ct], 0, 0, 0);

        // D row (M dim) = time t; D col = rho = w*64 + ct*16 + r16
        const int trow0 = (int)((rowbase + rt * 16 + kq * 4) & 1023);
#pragma unroll
        for (int ct = 0; ct < 4; ++ct) {
            // ct_off: ttp=(4w+ct)>>1 -> *1024 ; (ct&1) -> *8
            const size_t ct_off = (size_t)(2 * w + (ct >> 1)) * 1024 + (size_t)(ct & 1) * 8;
#pragma unroll
            for (int rr = 0; rr < 4; ++rr) {
                char* dst = (char*)xws + gm_base + (size_t)(trow0 + rr) * 8192
                            + ct_off + lane_off;
                *(__bf16*)dst = (__bf16)acc[ct][rr];
            }
        }
    }
}

// ---------------------------------------------------------------------------
// K2: LSTM scan. 8 INDEPENDENT 16-batch groups per 512-thread block (grid=2):
// one wave per group, no barriers, no shared state -> 2 waves/SIMD so
// co-resident waves fill each other's dependency stalls. Per-wave logic is
// verbatim from the passing R8 kernel; ring depth 4->2 (vmcnt(8), 16 KB/wave).
// ---------------------------------------------------------------------------
__global__ __launch_bounds__(512, 2)
void k2_scan(const __bf16* __restrict__ xws, const float* __restrict__ U,
             float* __restrict__ hout) {
    const int tid = threadIdx.x;
    const int wv  = tid >> 6;      // group-in-block 0..7
    const int l   = tid & 63;
    const int kq  = l >> 4;
    const int m   = l & 15;
    const int G   = blockIdx.x * 8 + wv;   // global group 0..15
    const int b0  = G * 16;

    __shared__ __align__(16) unsigned char ring[8][2][8192];   // 128KB, per-wave slices

    // A-frags: au[tt][ks][j] = sc * U[ks*32 + kq*8 + j][origcol(16tt + m)]
    bf16x8 au[16][2];
#pragma unroll
    for (int tt = 0; tt < 16; ++tt) {
        const int rho = 16 * tt + m;
        const int col = rho_origcol(rho);
        const float sc = ((rho >> 6) == 2) ? 1.f : 0.2f;
#pragma unroll
        for (int ks = 0; ks < 2; ++ks)
#pragma unroll
            for (int j = 0; j < 8; ++j)
                au[tt][ks][j] = (__bf16)(sc * U[(size_t)(ks * 32 + kq * 8 + j) * G4 + col]);
    }

    float c[2][2][4];
    float h[2][2][4];
#pragma unroll
    for (int s = 0; s < 2; ++s)
#pragma unroll
        for (int d2 = 0; d2 < 2; ++d2)
#pragma unroll
            for (int dl = 0; dl < 4; ++dl) { c[s][d2][dl] = 0.f; h[s][d2][dl] = 0.f; }

    bf16x8 bh0 = {};   // h == 0 at t=0
    bf16x8 bh1 = {};

    const char* gl = (const char*)xws + ((size_t)G << 23) + (size_t)l * 16;

    // prime the ring: slots 0..1 <- steps 0..1 (16 DMAs outstanding)
#pragma unroll
    for (int d = 0; d < 2; ++d)
#pragma unroll
        for (int tp = 0; tp < 8; ++tp)
            gld_lds16(gl + (size_t)d * 8192 + tp * 1024, &ring[wv][d][tp * 1024]);

    for (int t0 = 0; t0 < Tt; t0 += 2) {
#pragma unroll
        for (int s = 0; s < 2; ++s) {
            const int t = t0 + s;

            // ---- slot s ready when <=8 loads outstanding (1 newer slot)
            asm volatile("s_waitcnt vmcnt(8)" ::: "memory");

            // ---- consume slot s: 8 x ds_read_b128, unpack to acc (exact)
            f32x4v acc[16];
#pragma unroll
            for (int tp = 0; tp < 8; ++tp) {
                const uint4 d = *(const uint4*)&ring[wv][s][tp * 1024 + l * 16];
                acc[2 * tp][0]     = __builtin_bit_cast(float, d.x << 16);
                acc[2 * tp][1]     = __builtin_bit_cast(float, d.x & 0xFFFF0000u);
                acc[2 * tp][2]     = __builtin_bit_cast(float, d.y << 16);
                acc[2 * tp][3]     = __builtin_bit_cast(float, d.y & 0xFFFF0000u);
                acc[2 * tp + 1][0] = __builtin_bit_cast(float, d.z << 16);
                acc[2 * tp + 1][1] = __builtin_bit_cast(float, d.z & 0xFFFF0000u);
                acc[2 * tp + 1][2] = __builtin_bit_cast(float, d.w << 16);
                acc[2 * tp + 1][3] = __builtin_bit_cast(float, d.w & 0xFFFF0000u);
            }

            // ---- reissue slot s for step t+2 (clamped tail is dead/harmless)
            {
                int tpf = t + 2; if (tpf > Tt - 1) tpf = Tt - 1;
                const char* p = gl + (size_t)tpf * 8192;
#pragma unroll
                for (int tp = 0; tp < 8; ++tp)
                    gld_lds16(p + tp * 1024, &ring[wv][s][tp * 1024]);
            }

            // ---- z' = Ut.h + xw' : 32 MFMA, 16 independent chains of 2
#pragma unroll
            for (int tt = 0; tt < 16; ++tt) {
                acc[tt] = __builtin_amdgcn_mfma_f32_16x16x32_bf16(au[tt][0], bh0, acc[tt], 0, 0, 0);
                acc[tt] = __builtin_amdgcn_mfma_f32_16x16x32_bf16(au[tt][1], bh1, acc[tt], 0, 0, 0);
            }

            // ---- gates: register-local; i,f,o are already 0.2z+0.5
#pragma unroll
            for (int s2 = 0; s2 < 2; ++s2)
#pragma unroll
                for (int d2 = 0; d2 < 2; ++d2) {
                    const int ti = 2 * s2 + d2;
#pragma unroll
                    for (int dl = 0; dl < 4; ++dl) {
                        const float gi = fminf(fmaxf(acc[ti][dl],      0.f), 1.f);  // med3
                        const float gf = fminf(fmaxf(acc[4 + ti][dl],  0.f), 1.f);
                        const float gg = fmaxf(acc[8 + ti][dl], 0.f);
                        const float go = fminf(fmaxf(acc[12 + ti][dl], 0.f), 1.f);
                        const float cc = fmaf(gf, c[s2][d2][dl], gi * gg);
                        c[s2][d2][dl] = cc;
                        h[s2][d2][dl] = go * fmaxf(cc, 0.f);
                    }
                }

            // ---- pack next-step B-frags: bh0 = h[s2=0], bh1 = h[s2=1]
#pragma unroll
            for (int d2 = 0; d2 < 2; ++d2)
#pragma unroll
                for (int dl = 0; dl < 4; ++dl) {
                    bh0[4 * d2 + dl] = (__bf16)h[0][d2][dl];
                    bh1[4 * d2 + dl] = (__bf16)h[1][d2][dl];
                }
        }
    }

    // final h: hidx = 32*s2 + 8*kq + 4*d2 + dl
#pragma unroll
    for (int s2 = 0; s2 < 2; ++s2)
#pragma unroll
        for (int d2 = 0; d2 < 2; ++d2)
#pragma unroll
            for (int dl = 0; dl < 4; ++dl)
                hout[(size_t)(b0 + m) * Hh + 32 * s2 + 8 * kq + 4 * d2 + dl] = h[s2][d2][dl];
}

// ---------------------------------------------------------------------------
// K3: out[r,:] = softmax(h[r,:] @ Wd + bd). One block, thread = batch row.
// ---------------------------------------------------------------------------
__global__ __launch_bounds__(256)
void k3_dense(const float* __restrict__ hin, const float* __restrict__ Wd,
              const float* __restrict__ bd, float* __restrict__ out) {
    __shared__ float wd[Hh * NOUT];
    __shared__ float bds[NOUT];
    for (int i = threadIdx.x; i < Hh * NOUT; i += blockDim.x) wd[i] = Wd[i];
    if (threadIdx.x < NOUT) bds[threadIdx.x] = bd[threadIdx.x];
    __syncthreads();

    const int r = threadIdx.x;
    if (r < Bsz) {
        float hrow[Hh];
#pragma unroll
        for (int j = 0; j < Hh; ++j) hrow[j] = hin[(size_t)r * Hh + j];
        float logits[NOUT];
#pragma unroll
        for (int o = 0; o < NOUT; ++o) {
            float acc = bds[o];
#pragma unroll
            for (int j = 0; j < Hh; ++j) acc = fmaf(hrow[j], wd[j * NOUT + o], acc);
            logits[o] = acc;
        }
        float mx = logits[0];
#pragma unroll
        for (int o = 1; o < NOUT; ++o) mx = fmaxf(mx, logits[o]);
        float s = 0.f;
#pragma unroll
        for (int o = 0; o < NOUT; ++o) { logits[o] = expf(logits[o] - mx); s += logits[o]; }
        const float inv = 1.f / s;
#pragma unroll
        for (int o = 0; o < NOUT; ++o) out[(size_t)r * NOUT + o] = logits[o] * inv;
    }
}

// ---------------------------------------------------------------------------
extern "C" void kernel_launch(void* const* d_in, const int* in_sizes, int n_in,
                              void* d_out, int out_size, void* d_ws, size_t ws_size,
                              hipStream_t stream) {
    const float* x  = (const float*)d_in[0];
    const float* W  = (const float*)d_in[1];
    const float* U  = (const float*)d_in[2];
    const float* b  = (const float*)d_in[3];
    const float* Wd = (const float*)d_in[4];
    const float* bd = (const float*)d_in[5];
    float* out = (float*)d_out;

    const size_t xw_bytes = (size_t)Bsz * Tt * G4 * sizeof(__bf16);   // 128 MiB
    __bf16* xws   = (__bf16*)d_ws;
    float*  hbuf  = (float*)((char*)d_ws + xw_bytes);                 // 64 KB
    __bf16* Wt    = (__bf16*)((char*)hbuf + (size_t)Bsz * Hh * sizeof(float));
    float*  bias2 = (float*)((char*)Wt + (size_t)G4 * Dd * sizeof(__bf16));

    k0_prep<<<G4, Dd, 0, stream>>>(W, b, Wt, bias2);
    k1_mfma<<<(Bsz * Tt) / (16 * K1_RT), 256, 0, stream>>>(x, Wt, bias2, xws);
    k2_scan<<<2, 512, 0, stream>>>(xws, U, hbuf);
    k3_dense<<<1, 256, 0, stream>>>(hbuf, Wd, bd, out);
}

// Round 11
// 586.848 us; speedup vs baseline: 3.3661x; 3.3661x over previous
//
#include <hip/hip_runtime.h>
#include <hip/hip_bf16.h>

#define Hh   64      // LSTM hidden
#define G4   256     // 4*H gate width
#define Dd   128     // input feature dim
#define Bsz  256     // batch
#define Tt   1024    // time steps
#define NOUT 10      // dense classes

typedef __bf16  bf16x8 __attribute__((ext_vector_type(8)));
typedef __bf16  bf16x4 __attribute__((ext_vector_type(4)));
typedef float   f32x4v __attribute__((ext_vector_type(4)));

// rho = 64g + 16w + 4kq + r  <->  original gate column = 64g + hidx with
// hidx = 32(w>>1) + 8kq + 4(w&1) + r.  Bit-identical to the R8 function.
__device__ __forceinline__ int rho_origcol(int rho) {
    const int g  = rho >> 6;
    const int s  = (rho >> 5) & 1;
    const int d2 = (rho >> 4) & 1;
    const int kq = (rho >> 2) & 3;
    const int dl = rho & 3;
    return g * 64 + (32 * s + 8 * kq + 4 * d2 + dl);
}

// xws layout (bf16): byte(b,t,rho) = (b>>4)<<23 + t*8192 + w_*2048 + g_*512
//                    + kq_*128 + (b&15)*8 + r_*2   with rho = 64g_+16w_+4kq_+r_.
// k2 wave w's per-step slice = the 2KB at w*2048 (two 1KB coalesced DMAs).

__device__ __forceinline__ void gld_lds16(const void* g, void* l) {
    __builtin_amdgcn_global_load_lds(
        (const __attribute__((address_space(1))) unsigned int*)g,
        (__attribute__((address_space(3))) unsigned int*)l, 16, 0, 0);
}

// ---------------------------------------------------------------------------
// K0: Wt[rho][k] = bf16(scale * W[k][origcol]), bias2[rho] = scale*b + offs.
// scale = 0.2 for i,f,o gates (hard-sigmoid pre-scale), 1 for g gate.
// ---------------------------------------------------------------------------
__global__ __launch_bounds__(128)
void k0_prep(const float* __restrict__ W, const float* __restrict__ b,
             __bf16* __restrict__ Wt, float* __restrict__ bias2) {
    const int rho = blockIdx.x;
    const int k   = threadIdx.x;
    const int col = rho_origcol(rho);
    const bool isg = ((rho >> 6) == 2);
    const float sc = isg ? 1.f : 0.2f;
    Wt[(size_t)rho * Dd + k] = (__bf16)(sc * W[(size_t)k * G4 + col]);
    if (k == 0) bias2[rho] = sc * b[col] + (isg ? 0.f : 0.5f);
}

// ---------------------------------------------------------------------------
// K1: xw = x @ Wt + bias2 via MFMA, stored into the k2-native xws layout.
// k1's D col = rho = 64*w1 + 16*ct + r16 -> g_=w1, w_=ct, kq_=r16>>2, r_=r16&3.
// ---------------------------------------------------------------------------
#define K1_RT 8   // 128 rows/block; one batch per block (128 <= 1024)

__global__ __launch_bounds__(256)
void k1_mfma(const float* __restrict__ x, const __bf16* __restrict__ Wt,
             const float* __restrict__ bias, __bf16* __restrict__ xws) {
    const int tid = threadIdx.x;
    const int w   = tid >> 6;      // wave id w1
    const int l   = tid & 63;
    const int r16 = l & 15;
    const int kq  = l >> 4;
    const size_t rowbase = (size_t)blockIdx.x * (16 * K1_RT);

    const int bb = (int)(rowbase >> 10);            // batch (uniform per block)
    const size_t gm_base = ((size_t)(bb >> 4) << 23);
    const int lane_off = w * 512 + (r16 >> 2) * 128 + (bb & 15) * 8 + (r16 & 3) * 2;

    bf16x8 bfr[4][4];
    float  bval[4];
#pragma unroll
    for (int ct = 0; ct < 4; ++ct) {
        const int col = w * 64 + ct * 16 + r16;
        const __bf16* wp = Wt + (size_t)col * Dd + kq * 8;
#pragma unroll
        for (int kk = 0; kk < 4; ++kk)
            bfr[ct][kk] = *(const bf16x8*)(wp + kk * 32);
        bval[ct] = bias[col];
    }

    for (int rt = 0; rt < K1_RT; ++rt) {
        const size_t arow = rowbase + rt * 16 + r16;
        const float* xr = x + arow * Dd + kq * 8;
        bf16x8 afr[4];
#pragma unroll
        for (int kk = 0; kk < 4; ++kk) {
            const float4 lo = *(const float4*)(xr + kk * 32);
            const float4 hi = *(const float4*)(xr + kk * 32 + 4);
            afr[kk][0] = (__bf16)lo.x; afr[kk][1] = (__bf16)lo.y;
            afr[kk][2] = (__bf16)lo.z; afr[kk][3] = (__bf16)lo.w;
            afr[kk][4] = (__bf16)hi.x; afr[kk][5] = (__bf16)hi.y;
            afr[kk][6] = (__bf16)hi.z; afr[kk][7] = (__bf16)hi.w;
        }
        f32x4v acc[4];
#pragma unroll
        for (int ct = 0; ct < 4; ++ct)
            acc[ct] = (f32x4v){bval[ct], bval[ct], bval[ct], bval[ct]};
#pragma unroll
        for (int ct = 0; ct < 4; ++ct)
#pragma unroll
            for (int kk = 0; kk < 4; ++kk)
                acc[ct] = __builtin_amdgcn_mfma_f32_16x16x32_bf16(
                              afr[kk], bfr[ct][kk], acc[ct], 0, 0, 0);

        // D row = time (4*kq + rr within the 16-row tile), col = rho
        const int trow0 = (int)((rowbase + rt * 16 + kq * 4) & 1023);
#pragma unroll
        for (int ct = 0; ct < 4; ++ct) {
#pragma unroll
            for (int rr = 0; rr < 4; ++rr) {
                char* dst = (char*)xws + gm_base + (size_t)(trow0 + rr) * 8192
                            + (size_t)ct * 2048 + lane_off;
                *(__bf16*)dst = (__bf16)acc[ct][rr];
            }
        }
    }
}

// ---------------------------------------------------------------------------
// K2: LSTM scan, 4 cooperating waves per 16-batch group, 1 group/block,
// 16 blocks. Wave w owns tiles (g,w), g=0..3: lane (kq,m) gets all 4 gates
// of hidx = 32(w>>1)+8kq+4(w&1)+r for batch m -> gate math register-local.
// One h-exchange per step through padded LDS + plain __syncthreads().
// xw staged via superstep-batched global_load_lds DMA (16 issues / 8 steps
// into per-wave private ring slices, depth-2 supersteps); every step's
// __syncthreads drains vmcnt, so no asm waitcnt is needed anywhere.
// ---------------------------------------------------------------------------
#define SST 8   // steps per superstep

__global__ __launch_bounds__(256, 1)
void k2_scan(const __bf16* __restrict__ xws, const float* __restrict__ U,
             float* __restrict__ hout) {
    const int tid = threadIdx.x;
    const int w   = tid >> 6;       // wave 0..3
    const int l   = tid & 63;
    const int kq  = l >> 4;
    const int m   = l & 15;
    const int s_  = w >> 1, d2 = w & 1;
    const int G   = blockIdx.x;     // group 0..15

    __shared__ __align__(16) unsigned char ring[4][2][SST][2048];  // 128KB
    __shared__ __align__(16) __bf16 hx[2][16][72];                 // 4.5KB, padded rows

    // A-frags: au[g][ks][j] = sc_g * U[32ks + 8kq + j][origcol(64g+16w+m)]
    bf16x8 au[4][2];
#pragma unroll
    for (int g = 0; g < 4; ++g) {
        const float sc = (g == 2) ? 1.f : 0.2f;
        const int col = rho_origcol(64 * g + 16 * w + m);
#pragma unroll
        for (int ks = 0; ks < 2; ++ks)
#pragma unroll
            for (int j = 0; j < 8; ++j)
                au[g][ks][j] = (__bf16)(sc * U[(size_t)(ks * 32 + kq * 8 + j) * G4 + col]);
    }

    float c4[4]  = {0.f, 0.f, 0.f, 0.f};
    float hv4[4] = {0.f, 0.f, 0.f, 0.f};
    bf16x8 bh0 = {};    // h == 0 at t = 0
    bf16x8 bh1 = {};

    const char* gl = (const char*)xws + ((size_t)G << 23)
                     + (size_t)w * 2048 + (size_t)l * 16;

    // prologue: buf0 <- steps 0..7; barrier drains the DMAs
#pragma unroll
    for (int stp = 0; stp < SST; ++stp)
#pragma unroll
        for (int gg = 0; gg < 2; ++gg)
            gld_lds16(gl + (size_t)stp * 8192 + gg * 1024,
                      &ring[w][0][stp][gg * 1024]);
    __syncthreads();

    for (int S = 0; S < Tt / SST; ++S) {
        const int cur = S & 1;

        // issue next superstep's 16 DMAs into buf[cur^1] (consumed in S-1,
        // and this wave's reads of it completed before its last barrier)
        {
            int tn0 = (S + 1) * SST;
            if (tn0 > Tt - SST) tn0 = Tt - SST;   // tail: reload last steps (dead)
            const char* p = gl + (size_t)tn0 * 8192;
#pragma unroll
            for (int stp = 0; stp < SST; ++stp)
#pragma unroll
                for (int gg = 0; gg < 2; ++gg)
                    gld_lds16(p + (size_t)stp * 8192 + gg * 1024,
                              &ring[w][cur ^ 1][stp][gg * 1024]);
        }

#pragma unroll
        for (int stp = 0; stp < SST; ++stp) {
            const int par = stp & 1;    // (8S+stp)&1 == stp&1

            // ---- C init: 4x ds_read_b64 + exact bf16->f32 unpack
            f32x4v acc[4];
#pragma unroll
            for (int g = 0; g < 4; ++g) {
                const uint2 dz = *(const uint2*)&ring[w][cur][stp][g * 512
                                                                   + kq * 128 + m * 8];
                acc[g][0] = __builtin_bit_cast(float, dz.x << 16);
                acc[g][1] = __builtin_bit_cast(float, dz.x & 0xFFFF0000u);
                acc[g][2] = __builtin_bit_cast(float, dz.y << 16);
                acc[g][3] = __builtin_bit_cast(float, dz.y & 0xFFFF0000u);
            }

            // ---- z = Ut.h + xw : 8 MFMA (4 tiles x K=64)
#pragma unroll
            for (int g = 0; g < 4; ++g) {
                acc[g] = __builtin_amdgcn_mfma_f32_16x16x32_bf16(au[g][0], bh0, acc[g], 0, 0, 0);
                acc[g] = __builtin_amdgcn_mfma_f32_16x16x32_bf16(au[g][1], bh1, acc[g], 0, 0, 0);
            }

            // ---- gates (lane-local; i,f,o already 0.2z+0.5)
            bf16x4 hb;
#pragma unroll
            for (int r = 0; r < 4; ++r) {
                const float gi = fminf(fmaxf(acc[0][r], 0.f), 1.f);
                const float gf = fminf(fmaxf(acc[1][r], 0.f), 1.f);
                const float gg = fmaxf(acc[2][r], 0.f);
                const float go = fminf(fmaxf(acc[3][r], 0.f), 1.f);
                c4[r] = fmaf(gf, c4[r], gi * gg);
                hv4[r] = go * fmaxf(c4[r], 0.f);
                hb[r] = (__bf16)hv4[r];
            }

            // ---- h exchange (one barrier per step, full fence)
            *(bf16x4*)&hx[par][m][32 * s_ + 8 * kq + 4 * d2] = hb;
            __syncthreads();
            bh0 = *(const bf16x8*)&hx[par][m][8 * kq];
            bh1 = *(const bf16x8*)&hx[par][m][32 + 8 * kq];
        }
    }

    // final h (f32, local): hidx = 32s_ + 8kq + 4d2 + r
#pragma unroll
    for (int r = 0; r < 4; ++r)
        hout[(size_t)(G * 16 + m) * Hh + 32 * s_ + 8 * kq + 4 * d2 + r] = hv4[r];
}

// ---------------------------------------------------------------------------
// K3: out[r,:] = softmax(h[r,:] @ Wd + bd). One block, thread = batch row.
// ---------------------------------------------------------------------------
__global__ __launch_bounds__(256)
void k3_dense(const float* __restrict__ hin, const float* __restrict__ Wd,
              const float* __restrict__ bd, float* __restrict__ out) {
    __shared__ float wd[Hh * NOUT];
    __shared__ float bds[NOUT];
    for (int i = threadIdx.x; i < Hh * NOUT; i += blockDim.x) wd[i] = Wd[i];
    if (threadIdx.x < NOUT) bds[threadIdx.x] = bd[threadIdx.x];
    __syncthreads();

    const int r = threadIdx.x;
    if (r < Bsz) {
        float hrow[Hh];
#pragma unroll
        for (int j = 0; j < Hh; ++j) hrow[j] = hin[(size_t)r * Hh + j];
        float logits[NOUT];
#pragma unroll
        for (int o = 0; o < NOUT; ++o) {
            float acc = bds[o];
#pragma unroll
            for (int j = 0; j < Hh; ++j) acc = fmaf(hrow[j], wd[j * NOUT + o], acc);
            logits[o] = acc;
        }
        float mx = logits[0];
#pragma unroll
        for (int o = 1; o < NOUT; ++o) mx = fmaxf(mx, logits[o]);
        float s = 0.f;
#pragma unroll
        for (int o = 0; o < NOUT; ++o) { logits[o] = expf(logits[o] - mx); s += logits[o]; }
        const float inv = 1.f / s;
#pragma unroll
        for (int o = 0; o < NOUT; ++o) out[(size_t)r * NOUT + o] = logits[o] * inv;
    }
}

// ---------------------------------------------------------------------------
extern "C" void kernel_launch(void* const* d_in, const int* in_sizes, int n_in,
                              void* d_out, int out_size, void* d_ws, size_t ws_size,
                              hipStream_t stream) {
    const float* x  = (const float*)d_in[0];
    const float* W  = (const float*)d_in[1];
    const float* U  = (const float*)d_in[2];
    const float* b  = (const float*)d_in[3];
    const float* Wd = (const float*)d_in[4];
    const float* bd = (const float*)d_in[5];
    float* out = (float*)d_out;

    const size_t xw_bytes = (size_t)Bsz * Tt * G4 * sizeof(__bf16);   // 128 MiB
    __bf16* xws   = (__bf16*)d_ws;
    float*  hbuf  = (float*)((char*)d_ws + xw_bytes);                 // 64 KB
    __bf16* Wt    = (__bf16*)((char*)hbuf + (size_t)Bsz * Hh * sizeof(float));
    float*  bias2 = (float*)((char*)Wt + (size_t)G4 * Dd * sizeof(__bf16));

    k0_prep<<<G4, Dd, 0, stream>>>(W, b, Wt, bias2);
    k1_mfma<<<(Bsz * Tt) / (16 * K1_RT), 256, 0, stream>>>(x, Wt, bias2, xws);
    k2_scan<<<Bsz / 16, 256, 0, stream>>>(xws, U, hbuf);
    k3_dense<<<1, 256, 0, stream>>>(hbuf, Wd, bd, out);
}

// Round 12
// 572.394 us; speedup vs baseline: 3.4511x; 1.0253x over previous
//
#include <hip/hip_runtime.h>
#include <hip/hip_bf16.h>

#define Hh   64      // LSTM hidden
#define G4   256     // 4*H gate width
#define Dd   128     // input feature dim
#define Bsz  256     // batch
#define Tt   1024    // time steps
#define NOUT 10      // dense classes

typedef __bf16  bf16x8 __attribute__((ext_vector_type(8)));
typedef __bf16  bf16x4 __attribute__((ext_vector_type(4)));
typedef float   f32x4v __attribute__((ext_vector_type(4)));

// rho = 64g + 16w + 4kq + r  <->  original gate column = 64g + hidx with
// hidx = 32(w>>1) + 8kq + 4(w&1) + r.
__device__ __forceinline__ int rho_origcol(int rho) {
    const int g  = rho >> 6;
    const int s  = (rho >> 5) & 1;
    const int d2 = (rho >> 4) & 1;
    const int kq = (rho >> 2) & 3;
    const int dl = rho & 3;
    return g * 64 + (32 * s + 8 * kq + 4 * d2 + dl);
}

// xws layout (bf16): byte(b,t,rho) = (b>>4)<<23 + t*8192 + w_*2048 + g_*512
//                    + kq_*128 + (b&15)*8 + r_*2   with rho = 64g_+16w_+4kq_+r_.
// k2 wave w's per-step slice = the 2KB at w*2048 (two 1KB coalesced DMAs).

__device__ __forceinline__ void gld_lds16(const void* g, void* l) {
    __builtin_amdgcn_global_load_lds(
        (const __attribute__((address_space(1))) unsigned int*)g,
        (__attribute__((address_space(3))) unsigned int*)l, 16, 0, 0);
}

// ---------------------------------------------------------------------------
// K0: Wt[rho][k] = bf16(scale * W[k][origcol]), bias2[rho] = scale*b + offs.
// scale = 0.2 for i,f,o gates (hard-sigmoid pre-scale), 1 for g gate.
// ---------------------------------------------------------------------------
__global__ __launch_bounds__(128)
void k0_prep(const float* __restrict__ W, const float* __restrict__ b,
             __bf16* __restrict__ Wt, float* __restrict__ bias2) {
    const int rho = blockIdx.x;
    const int k   = threadIdx.x;
    const int col = rho_origcol(rho);
    const bool isg = ((rho >> 6) == 2);
    const float sc = isg ? 1.f : 0.2f;
    Wt[(size_t)rho * Dd + k] = (__bf16)(sc * W[(size_t)k * G4 + col]);
    if (k == 0) bias2[rho] = sc * b[col] + (isg ? 0.f : 0.5f);
}

// ---------------------------------------------------------------------------
// K1: xw = x @ Wt + bias2 via MFMA, stored into the k2-native xws layout.
// (verbatim from the passing R11 kernel)
// ---------------------------------------------------------------------------
#define K1_RT 8

__global__ __launch_bounds__(256)
void k1_mfma(const float* __restrict__ x, const __bf16* __restrict__ Wt,
             const float* __restrict__ bias, __bf16* __restrict__ xws) {
    const int tid = threadIdx.x;
    const int w   = tid >> 6;      // wave id w1
    const int l   = tid & 63;
    const int r16 = l & 15;
    const int kq  = l >> 4;
    const size_t rowbase = (size_t)blockIdx.x * (16 * K1_RT);

    const int bb = (int)(rowbase >> 10);            // batch (uniform per block)
    const size_t gm_base = ((size_t)(bb >> 4) << 23);
    const int lane_off = w * 512 + (r16 >> 2) * 128 + (bb & 15) * 8 + (r16 & 3) * 2;

    bf16x8 bfr[4][4];
    float  bval[4];
#pragma unroll
    for (int ct = 0; ct < 4; ++ct) {
        const int col = w * 64 + ct * 16 + r16;
        const __bf16* wp = Wt + (size_t)col * Dd + kq * 8;
#pragma unroll
        for (int kk = 0; kk < 4; ++kk)
            bfr[ct][kk] = *(const bf16x8*)(wp + kk * 32);
        bval[ct] = bias[col];
    }

    for (int rt = 0; rt < K1_RT; ++rt) {
        const size_t arow = rowbase + rt * 16 + r16;
        const float* xr = x + arow * Dd + kq * 8;
        bf16x8 afr[4];
#pragma unroll
        for (int kk = 0; kk < 4; ++kk) {
            const float4 lo = *(const float4*)(xr + kk * 32);
            const float4 hi = *(const float4*)(xr + kk * 32 + 4);
            afr[kk][0] = (__bf16)lo.x; afr[kk][1] = (__bf16)lo.y;
            afr[kk][2] = (__bf16)lo.z; afr[kk][3] = (__bf16)lo.w;
            afr[kk][4] = (__bf16)hi.x; afr[kk][5] = (__bf16)hi.y;
            afr[kk][6] = (__bf16)hi.z; afr[kk][7] = (__bf16)hi.w;
        }
        f32x4v acc[4];
#pragma unroll
        for (int ct = 0; ct < 4; ++ct)
            acc[ct] = (f32x4v){bval[ct], bval[ct], bval[ct], bval[ct]};
#pragma unroll
        for (int ct = 0; ct < 4; ++ct)
#pragma unroll
            for (int kk = 0; kk < 4; ++kk)
                acc[ct] = __builtin_amdgcn_mfma_f32_16x16x32_bf16(
                              afr[kk], bfr[ct][kk], acc[ct], 0, 0, 0);

        const int trow0 = (int)((rowbase + rt * 16 + kq * 4) & 1023);
#pragma unroll
        for (int ct = 0; ct < 4; ++ct) {
#pragma unroll
            for (int rr = 0; rr < 4; ++rr) {
                char* dst = (char*)xws + gm_base + (size_t)(trow0 + rr) * 8192
                            + (size_t)ct * 2048 + lane_off;
                *(__bf16*)dst = (__bf16)acc[ct][rr];
            }
        }
    }
}

// ---------------------------------------------------------------------------
// K2: LSTM scan, 4 cooperating waves per 16-batch group, 1 group/block,
// 16 blocks. Same decomposition and double-buffered superstep DMA ring as
// the passing R11 kernel. Sync upgraded per T4: raw lgkm-only barrier per
// step (no vmcnt drain) + ONE counted vmcnt(16) per superstep, so the 16
// next-superstep DMAs stay in flight across all 8 steps (~8000cy >> HBM
// latency). Next-superstep DMAs are issued at the END of the superstep,
// after this wave's lgkmcnt(0) drained its ring reads (same-wave order
// makes the buffer overwrite safe; ring slices are per-wave private).
// ---------------------------------------------------------------------------
#define SST 8   // steps per superstep

__global__ __launch_bounds__(256, 1)
void k2_scan(const __bf16* __restrict__ xws, const float* __restrict__ U,
             float* __restrict__ hout) {
    const int tid = threadIdx.x;
    const int w   = tid >> 6;       // wave 0..3
    const int l   = tid & 63;
    const int kq  = l >> 4;
    const int m   = l & 15;
    const int s_  = w >> 1, d2 = w & 1;
    const int G   = blockIdx.x;     // group 0..15

    __shared__ __align__(16) unsigned char ring[4][2][SST][2048];  // 128KB
    __shared__ __align__(16) __bf16 hx[2][16][72];                 // 4.5KB

    // A-frags: au[g][ks][j] = sc_g * U[32ks + 8kq + j][origcol(64g+16w+m)]
    bf16x8 au[4][2];
#pragma unroll
    for (int g = 0; g < 4; ++g) {
        const float sc = (g == 2) ? 1.f : 0.2f;
        const int col = rho_origcol(64 * g + 16 * w + m);
#pragma unroll
        for (int ks = 0; ks < 2; ++ks)
#pragma unroll
            for (int j = 0; j < 8; ++j)
                au[g][ks][j] = (__bf16)(sc * U[(size_t)(ks * 32 + kq * 8 + j) * G4 + col]);
    }

    float c4[4]  = {0.f, 0.f, 0.f, 0.f};
    float hv4[4] = {0.f, 0.f, 0.f, 0.f};
    bf16x8 bh0 = {};    // h == 0 at t = 0
    bf16x8 bh1 = {};

    const char* gl = (const char*)xws + ((size_t)G << 23)
                     + (size_t)w * 2048 + (size_t)l * 16;

    // prologue: issue buf0 (steps 0..7) and buf1 (steps 8..15) -> 32 in flight
#pragma unroll
    for (int buf = 0; buf < 2; ++buf)
#pragma unroll
        for (int stp = 0; stp < SST; ++stp)
#pragma unroll
            for (int gg = 0; gg < 2; ++gg)
                gld_lds16(gl + (size_t)(buf * SST + stp) * 8192 + gg * 1024,
                          &ring[w][buf][stp][gg * 1024]);
    __syncthreads();   // once at t=0: full drain + block sync (cheap, outside loop)

    for (int S = 0; S < Tt / SST; ++S) {
        const int cur = S & 1;

        // buf[cur] ready when <=16 outstanding (only next superstep's remain)
        asm volatile("s_waitcnt vmcnt(16)" ::: "memory");
        __builtin_amdgcn_sched_barrier(0);

#pragma unroll
        for (int stp = 0; stp < SST; ++stp) {
            const int par = stp & 1;    // (8S+stp)&1 == stp&1

            // ---- C init: 4x ds_read_b64 + exact bf16->f32 unpack
            f32x4v acc[4];
#pragma unroll
            for (int g = 0; g < 4; ++g) {
                const uint2 dz = *(const uint2*)&ring[w][cur][stp][g * 512
                                                                   + kq * 128 + m * 8];
                acc[g][0] = __builtin_bit_cast(float, dz.x << 16);
                acc[g][1] = __builtin_bit_cast(float, dz.x & 0xFFFF0000u);
                acc[g][2] = __builtin_bit_cast(float, dz.y << 16);
                acc[g][3] = __builtin_bit_cast(float, dz.y & 0xFFFF0000u);
            }

            // ---- z = Ut.h + xw : 8 MFMA (4 tiles x K=64)
#pragma unroll
            for (int g = 0; g < 4; ++g) {
                acc[g] = __builtin_amdgcn_mfma_f32_16x16x32_bf16(au[g][0], bh0, acc[g], 0, 0, 0);
                acc[g] = __builtin_amdgcn_mfma_f32_16x16x32_bf16(au[g][1], bh1, acc[g], 0, 0, 0);
            }

            // ---- gates (lane-local; i,f,o already 0.2z+0.5)
            bf16x4 hb;
#pragma unroll
            for (int r = 0; r < 4; ++r) {
                const float gi = fminf(fmaxf(acc[0][r], 0.f), 1.f);
                const float gf = fminf(fmaxf(acc[1][r], 0.f), 1.f);
                const float gg = fmaxf(acc[2][r], 0.f);
                const float go = fminf(fmaxf(acc[3][r], 0.f), 1.f);
                c4[r] = fmaf(gf, c4[r], gi * gg);
                hv4[r] = go * fmaxf(c4[r], 0.f);
                hb[r] = (__bf16)hv4[r];
            }

            // ---- h exchange: write -> lgkm drain -> raw barrier (vmcnt LIVE)
            *(bf16x4*)&hx[par][m][32 * s_ + 8 * kq + 4 * d2] = hb;
            asm volatile("s_waitcnt lgkmcnt(0)" ::: "memory");
            __builtin_amdgcn_sched_barrier(0);
            __builtin_amdgcn_s_barrier();
            __builtin_amdgcn_sched_barrier(0);

            // ---- next-step B-frags
            bh0 = *(const bf16x8*)&hx[par][m][8 * kq];
            bh1 = *(const bf16x8*)&hx[par][m][32 + 8 * kq];
        }

        // ---- issue superstep S+2 into buf[cur] (its reads are drained:
        // this wave's last lgkmcnt(0) covered all ring ds_reads; per-wave
        // private slice so no cross-wave hazard). Tail issues are dead.
        {
            int tn0 = (S + 2) * SST;
            if (tn0 > Tt - SST) tn0 = Tt - SST;
            const char* p = gl + (size_t)tn0 * 8192;
#pragma unroll
            for (int stp = 0; stp < SST; ++stp)
#pragma unroll
                for (int gg = 0; gg < 2; ++gg)
                    gld_lds16(p + (size_t)stp * 8192 + gg * 1024,
                              &ring[w][cur][stp][gg * 1024]);
        }
    }

    // final h (f32, in registers): hidx = 32s_ + 8kq + 4d2 + r
#pragma unroll
    for (int r = 0; r < 4; ++r)
        hout[(size_t)(G * 16 + m) * Hh + 32 * s_ + 8 * kq + 4 * d2 + r] = hv4[r];
}

// ---------------------------------------------------------------------------
// K3: out[r,:] = softmax(h[r,:] @ Wd + bd). One block, thread = batch row.
// ---------------------------------------------------------------------------
__global__ __launch_bounds__(256)
void k3_dense(const float* __restrict__ hin, const float* __restrict__ Wd,
              const float* __restrict__ bd, float* __restrict__ out) {
    __shared__ float wd[Hh * NOUT];
    __shared__ float bds[NOUT];
    for (int i = threadIdx.x; i < Hh * NOUT; i += blockDim.x) wd[i] = Wd[i];
    if (threadIdx.x < NOUT) bds[threadIdx.x] = bd[threadIdx.x];
    __syncthreads();

    const int r = threadIdx.x;
    if (r < Bsz) {
        float hrow[Hh];
#pragma unroll
        for (int j = 0; j < Hh; ++j) hrow[j] = hin[(size_t)r * Hh + j];
        float logits[NOUT];
#pragma unroll
        for (int o = 0; o < NOUT; ++o) {
            float acc = bds[o];
#pragma unroll
            for (int j = 0; j < Hh; ++j) acc = fmaf(hrow[j], wd[j * NOUT + o], acc);
            logits[o] = acc;
        }
        float mx = logits[0];
#pragma unroll
        for (int o = 1; o < NOUT; ++o) mx = fmaxf(mx, logits[o]);
        float s = 0.f;
#pragma unroll
        for (int o = 0; o < NOUT; ++o) { logits[o] = expf(logits[o] - mx); s += logits[o]; }
        const float inv = 1.f / s;
#pragma unroll
        for (int o = 0; o < NOUT; ++o) out[(size_t)r * NOUT + o] = logits[o] * inv;
    }
}

// ---------------------------------------------------------------------------
extern "C" void kernel_launch(void* const* d_in, const int* in_sizes, int n_in,
                              void* d_out, int out_size, void* d_ws, size_t ws_size,
                              hipStream_t stream) {
    const float* x  = (const float*)d_in[0];
    const float* W  = (const float*)d_in[1];
    const float* U  = (const float*)d_in[2];
    const float* b  = (const float*)d_in[3];
    const float* Wd = (const float*)d_in[4];
    const float* bd = (const float*)d_in[5];
    float* out = (float*)d_out;

    const size_t xw_bytes = (size_t)Bsz * Tt * G4 * sizeof(__bf16);   // 128 MiB
    __bf16* xws   = (__bf16*)d_ws;
    float*  hbuf  = (float*)((char*)d_ws + xw_bytes);                 // 64 KB
    __bf16* Wt    = (__bf16*)((char*)hbuf + (size_t)Bsz * Hh * sizeof(float));
    float*  bias2 = (float*)((char*)Wt + (size_t)G4 * Dd * sizeof(__bf16));

    k0_prep<<<G4, Dd, 0, stream>>>(W, b, Wt, bias2);
    k1_mfma<<<(Bsz * Tt) / (16 * K1_RT), 256, 0, stream>>>(x, Wt, bias2, xws);
    k2_scan<<<Bsz / 16, 256, 0, stream>>>(xws, U, hbuf);
    k3_dense<<<1, 256, 0, stream>>>(hbuf, Wd, bd, out);
}

// Round 13
// 560.941 us; speedup vs baseline: 3.5215x; 1.0204x over previous
//
#include <hip/hip_runtime.h>
#include <hip/hip_bf16.h>

#define Hh   64      // LSTM hidden
#define G4   256     // 4*H gate width
#define Dd   128     // input feature dim
#define Bsz  256     // batch
#define Tt   1024    // time steps
#define NOUT 10      // dense classes

typedef __bf16  bf16x8 __attribute__((ext_vector_type(8)));
typedef __bf16  bf16x4 __attribute__((ext_vector_type(4)));
typedef float   f32x4v __attribute__((ext_vector_type(4)));

// rho = 64g + 16w + 4kq + r  <->  original gate column = 64g + hidx with
// hidx = 32(w>>1) + 8kq + 4(w&1) + r.
__device__ __forceinline__ int rho_origcol(int rho) {
    const int g  = rho >> 6;
    const int s  = (rho >> 5) & 1;
    const int d2 = (rho >> 4) & 1;
    const int kq = (rho >> 2) & 3;
    const int dl = rho & 3;
    return g * 64 + (32 * s + 8 * kq + 4 * d2 + dl);
}

// xws layout (bf16): byte(b,t,rho) = (b>>4)<<23 + t*8192 + w_*2048 + g_*512
//                    + kq_*128 + (b&15)*8 + r_*2   with rho = 64g_+16w_+4kq_+r_.

__device__ __forceinline__ void gld_lds16(const void* g, void* l) {
    __builtin_amdgcn_global_load_lds(
        (const __attribute__((address_space(1))) unsigned int*)g,
        (__attribute__((address_space(3))) unsigned int*)l, 16, 0, 0);
}

// ---------------------------------------------------------------------------
// K0: Wt[rho][k] = bf16(scale * W[k][origcol]), bias2[rho] = scale*b + offs.
// ---------------------------------------------------------------------------
__global__ __launch_bounds__(128)
void k0_prep(const float* __restrict__ W, const float* __restrict__ b,
             __bf16* __restrict__ Wt, float* __restrict__ bias2) {
    const int rho = blockIdx.x;
    const int k   = threadIdx.x;
    const int col = rho_origcol(rho);
    const bool isg = ((rho >> 6) == 2);
    const float sc = isg ? 1.f : 0.2f;
    Wt[(size_t)rho * Dd + k] = (__bf16)(sc * W[(size_t)k * G4 + col]);
    if (k == 0) bias2[rho] = sc * b[col] + (isg ? 0.f : 0.5f);
}

// ---------------------------------------------------------------------------
// K1: xw = x @ Wt + bias2 via MFMA, stored into the k2-native xws layout.
// (verbatim from the passing R12 kernel)
// ---------------------------------------------------------------------------
#define K1_RT 8

__global__ __launch_bounds__(256)
void k1_mfma(const float* __restrict__ x, const __bf16* __restrict__ Wt,
             const float* __restrict__ bias, __bf16* __restrict__ xws) {
    const int tid = threadIdx.x;
    const int w   = tid >> 6;
    const int l   = tid & 63;
    const int r16 = l & 15;
    const int kq  = l >> 4;
    const size_t rowbase = (size_t)blockIdx.x * (16 * K1_RT);

    const int bb = (int)(rowbase >> 10);
    const size_t gm_base = ((size_t)(bb >> 4) << 23);
    const int lane_off = w * 512 + (r16 >> 2) * 128 + (bb & 15) * 8 + (r16 & 3) * 2;

    bf16x8 bfr[4][4];
    float  bval[4];
#pragma unroll
    for (int ct = 0; ct < 4; ++ct) {
        const int col = w * 64 + ct * 16 + r16;
        const __bf16* wp = Wt + (size_t)col * Dd + kq * 8;
#pragma unroll
        for (int kk = 0; kk < 4; ++kk)
            bfr[ct][kk] = *(const bf16x8*)(wp + kk * 32);
        bval[ct] = bias[col];
    }

    for (int rt = 0; rt < K1_RT; ++rt) {
        const size_t arow = rowbase + rt * 16 + r16;
        const float* xr = x + arow * Dd + kq * 8;
        bf16x8 afr[4];
#pragma unroll
        for (int kk = 0; kk < 4; ++kk) {
            const float4 lo = *(const float4*)(xr + kk * 32);
            const float4 hi = *(const float4*)(xr + kk * 32 + 4);
            afr[kk][0] = (__bf16)lo.x; afr[kk][1] = (__bf16)lo.y;
            afr[kk][2] = (__bf16)lo.z; afr[kk][3] = (__bf16)lo.w;
            afr[kk][4] = (__bf16)hi.x; afr[kk][5] = (__bf16)hi.y;
            afr[kk][6] = (__bf16)hi.z; afr[kk][7] = (__bf16)hi.w;
        }
        f32x4v acc[4];
#pragma unroll
        for (int ct = 0; ct < 4; ++ct)
            acc[ct] = (f32x4v){bval[ct], bval[ct], bval[ct], bval[ct]};
#pragma unroll
        for (int ct = 0; ct < 4; ++ct)
#pragma unroll
            for (int kk = 0; kk < 4; ++kk)
                acc[ct] = __builtin_amdgcn_mfma_f32_16x16x32_bf16(
                              afr[kk], bfr[ct][kk], acc[ct], 0, 0, 0);

        const int trow0 = (int)((rowbase + rt * 16 + kq * 4) & 1023);
#pragma unroll
        for (int ct = 0; ct < 4; ++ct) {
#pragma unroll
            for (int rr = 0; rr < 4; ++rr) {
                char* dst = (char*)xws + gm_base + (size_t)(trow0 + rr) * 8192
                            + (size_t)ct * 2048 + lane_off;
                *(__bf16*)dst = (__bf16)acc[ct][rr];
            }
        }
    }
}

// ---------------------------------------------------------------------------
// K2: LSTM scan, 4 cooperating waves per 16-batch group, 1 group/block,
// 16 blocks. R12 structure with the step body software-rotated so the
// post-barrier critical window contains ONLY bh-read -> MFMA -> gates:
//  - C-init ds_reads for step t+1 are ISSUED before step t's barrier (raw
//    dz regs, unpack deferred past the barrier to overlap bh-read latency)
//  - counted lgkmcnt(4) before the barrier waits only for the hx write
//    (DS FIFO in-order per wave); prestage reads stay in flight
//  - superstep-crossing step skips prestage; superstep-top does one direct
//    C-init after the counted vmcnt(16)
// ---------------------------------------------------------------------------
#define SST 8   // steps per superstep

__global__ __launch_bounds__(256, 1)
void k2_scan(const __bf16* __restrict__ xws, const float* __restrict__ U,
             float* __restrict__ hout) {
    const int tid = threadIdx.x;
    const int w   = tid >> 6;       // wave 0..3
    const int l   = tid & 63;
    const int kq  = l >> 4;
    const int m   = l & 15;
    const int s_  = w >> 1, d2 = w & 1;
    const int G   = blockIdx.x;     // group 0..15

    __shared__ __align__(16) unsigned char ring[4][2][SST][2048];  // 128KB
    __shared__ __align__(16) __bf16 hx[2][16][72];                 // 4.5KB

    // A-frags: au[g][ks][j] = sc_g * U[32ks + 8kq + j][origcol(64g+16w+m)]
    bf16x8 au[4][2];
#pragma unroll
    for (int g = 0; g < 4; ++g) {
        const float sc = (g == 2) ? 1.f : 0.2f;
        const int col = rho_origcol(64 * g + 16 * w + m);
#pragma unroll
        for (int ks = 0; ks < 2; ++ks)
#pragma unroll
            for (int j = 0; j < 8; ++j)
                au[g][ks][j] = (__bf16)(sc * U[(size_t)(ks * 32 + kq * 8 + j) * G4 + col]);
    }

    float c4[4]  = {0.f, 0.f, 0.f, 0.f};
    float hv4[4] = {0.f, 0.f, 0.f, 0.f};

    // zero hx[1] (read by the very first step, rp = 1)
    {
        const bf16x4 z4 = {(__bf16)0.f, (__bf16)0.f, (__bf16)0.f, (__bf16)0.f};
        *(bf16x4*)&hx[1][m][32 * s_ + 8 * kq + 4 * d2] = z4;
    }

    const char* gl = (const char*)xws + ((size_t)G << 23)
                     + (size_t)w * 2048 + (size_t)l * 16;

    // prologue: issue buf0 (steps 0..7) and buf1 (steps 8..15) -> 32 in flight
#pragma unroll
    for (int buf = 0; buf < 2; ++buf)
#pragma unroll
        for (int stp = 0; stp < SST; ++stp)
#pragma unroll
            for (int gg = 0; gg < 2; ++gg)
                gld_lds16(gl + (size_t)(buf * SST + stp) * 8192 + gg * 1024,
                          &ring[w][buf][stp][gg * 1024]);
    __syncthreads();   // once: drains prologue DMAs + publishes hx[1] zeros

    uint2  dz[4];
    f32x4v accN[4];
    bf16x8 bh0, bh1;

    for (int S = 0; S < Tt / SST; ++S) {
        const int cur = S & 1;

        // buf[cur] ready when <=16 outstanding (only next superstep's remain)
        asm volatile("s_waitcnt vmcnt(16)" ::: "memory");
        __builtin_amdgcn_sched_barrier(0);

        // superstep-top C-init for stp 0 (once per 8 steps)
#pragma unroll
        for (int g = 0; g < 4; ++g)
            dz[g] = *(const uint2*)&ring[w][cur][0][g * 512 + kq * 128 + m * 8];
#pragma unroll
        for (int g = 0; g < 4; ++g) {
            accN[g][0] = __builtin_bit_cast(float, dz[g].x << 16);
            accN[g][1] = __builtin_bit_cast(float, dz[g].x & 0xFFFF0000u);
            accN[g][2] = __builtin_bit_cast(float, dz[g].y << 16);
            accN[g][3] = __builtin_bit_cast(float, dz[g].y & 0xFFFF0000u);
        }

#pragma unroll
        for (int stp = 0; stp < SST; ++stp) {
            const int rp = (stp + 1) & 1;   // parity written by previous step

            // ---- post-barrier critical path: bh read -> MFMA -> gates
            bh0 = *(const bf16x8*)&hx[rp][m][8 * kq];
            bh1 = *(const bf16x8*)&hx[rp][m][32 + 8 * kq];

            f32x4v acc[4];
#pragma unroll
            for (int g = 0; g < 4; ++g) {
                acc[g] = __builtin_amdgcn_mfma_f32_16x16x32_bf16(au[g][0], bh0, accN[g], 0, 0, 0);
                acc[g] = __builtin_amdgcn_mfma_f32_16x16x32_bf16(au[g][1], bh1, acc[g], 0, 0, 0);
            }

            bf16x4 hb;
#pragma unroll
            for (int r = 0; r < 4; ++r) {
                const float gi = __builtin_amdgcn_fmed3f(acc[0][r], 0.f, 1.f);
                const float gf = __builtin_amdgcn_fmed3f(acc[1][r], 0.f, 1.f);
                const float gg = fmaxf(acc[2][r], 0.f);
                const float go = __builtin_amdgcn_fmed3f(acc[3][r], 0.f, 1.f);
                c4[r] = fmaf(gf, c4[r], gi * gg);
                hv4[r] = go * fmaxf(c4[r], 0.f);
                hb[r] = (__bf16)hv4[r];
            }

            // ---- publish h (write FIRST so counted lgkm covers it)
            *(bf16x4*)&hx[stp & 1][m][32 * s_ + 8 * kq + 4 * d2] = hb;

            // ---- prestage next step's C reads (issue only; unpack later)
            if (stp < SST - 1) {
#pragma unroll
                for (int g = 0; g < 4; ++g)
                    dz[g] = *(const uint2*)&ring[w][cur][stp + 1][g * 512
                                                                  + kq * 128 + m * 8];
                asm volatile("s_waitcnt lgkmcnt(4)" ::: "memory");  // write drained
            } else {
                asm volatile("s_waitcnt lgkmcnt(0)" ::: "memory");
            }
            __builtin_amdgcn_sched_barrier(0);
            __builtin_amdgcn_s_barrier();
            __builtin_amdgcn_sched_barrier(0);

            // ---- deferred unpack (overlaps next step's bh-read latency)
            if (stp < SST - 1) {
#pragma unroll
                for (int g = 0; g < 4; ++g) {
                    accN[g][0] = __builtin_bit_cast(float, dz[g].x << 16);
                    accN[g][1] = __builtin_bit_cast(float, dz[g].x & 0xFFFF0000u);
                    accN[g][2] = __builtin_bit_cast(float, dz[g].y << 16);
                    accN[g][3] = __builtin_bit_cast(float, dz[g].y & 0xFFFF0000u);
                }
            }
        }

        // ---- issue superstep S+2 into buf[cur] (reads long retired)
        {
            int tn0 = (S + 2) * SST;
            if (tn0 > Tt - SST) tn0 = Tt - SST;
            const char* p = gl + (size_t)tn0 * 8192;
#pragma unroll
            for (int stp = 0; stp < SST; ++stp)
#pragma unroll
                for (int gg = 0; gg < 2; ++gg)
                    gld_lds16(p + (size_t)stp * 8192 + gg * 1024,
                              &ring[w][cur][stp][gg * 1024]);
        }
    }

    // final h (f32, in registers): hidx = 32s_ + 8kq + 4d2 + r
#pragma unroll
    for (int r = 0; r < 4; ++r)
        hout[(size_t)(G * 16 + m) * Hh + 32 * s_ + 8 * kq + 4 * d2 + r] = hv4[r];
}

// ---------------------------------------------------------------------------
// K3: out[r,:] = softmax(h[r,:] @ Wd + bd). One block, thread = batch row.
// ---------------------------------------------------------------------------
__global__ __launch_bounds__(256)
void k3_dense(const float* __restrict__ hin, const float* __restrict__ Wd,
              const float* __restrict__ bd, float* __restrict__ out) {
    __shared__ float wd[Hh * NOUT];
    __shared__ float bds[NOUT];
    for (int i = threadIdx.x; i < Hh * NOUT; i += blockDim.x) wd[i] = Wd[i];
    if (threadIdx.x < NOUT) bds[threadIdx.x] = bd[threadIdx.x];
    __syncthreads();

    const int r = threadIdx.x;
    if (r < Bsz) {
        float hrow[Hh];
#pragma unroll
        for (int j = 0; j < Hh; ++j) hrow[j] = hin[(size_t)r * Hh + j];
        float logits[NOUT];
#pragma unroll
        for (int o = 0; o < NOUT; ++o) {
            float acc = bds[o];
#pragma unroll
            for (int j = 0; j < Hh; ++j) acc = fmaf(hrow[j], wd[j * NOUT + o], acc);
            logits[o] = acc;
        }
        float mx = logits[0];
#pragma unroll
        for (int o = 1; o < NOUT; ++o) mx = fmaxf(mx, logits[o]);
        float s = 0.f;
#pragma unroll
        for (int o = 0; o < NOUT; ++o) { logits[o] = expf(logits[o] - mx); s += logits[o]; }
        const float inv = 1.f / s;
#pragma unroll
        for (int o = 0; o < NOUT; ++o) out[(size_t)r * NOUT + o] = logits[o] * inv;
    }
}

// ---------------------------------------------------------------------------
extern "C" void kernel_launch(void* const* d_in, const int* in_sizes, int n_in,
                              void* d_out, int out_size, void* d_ws, size_t ws_size,
                              hipStream_t stream) {
    const float* x  = (const float*)d_in[0];
    const float* W  = (const float*)d_in[1];
    const float* U  = (const float*)d_in[2];
    const float* b  = (const float*)d_in[3];
    const float* Wd = (const float*)d_in[4];
    const float* bd = (const float*)d_in[5];
    float* out = (float*)d_out;

    const size_t xw_bytes = (size_t)Bsz * Tt * G4 * sizeof(__bf16);   // 128 MiB
    __bf16* xws   = (__bf16*)d_ws;
    float*  hbuf  = (float*)((char*)d_ws + xw_bytes);                 // 64 KB
    __bf16* Wt    = (__bf16*)((char*)hbuf + (size_t)Bsz * Hh * sizeof(float));
    float*  bias2 = (float*)((char*)Wt + (size_t)G4 * Dd * sizeof(__bf16));

    k0_prep<<<G4, Dd, 0, stream>>>(W, b, Wt, bias2);
    k1_mfma<<<(Bsz * Tt) / (16 * K1_RT), 256, 0, stream>>>(x, Wt, bias2, xws);
    k2_scan<<<Bsz / 16, 256, 0, stream>>>(xws, U, hbuf);
    k3_dense<<<1, 256, 0, stream>>>(hbuf, Wd, bd, out);
}